// Round 4
// baseline (275.594 us; speedup 1.0000x reference)
//
#include <hip/hip_runtime.h>
#include <hip/hip_bf16.h>
#include <cstdint>

// ---------------------------------------------------------------------------
// AttentionModel: out = softmax((xWq^T+bq)(xWk^T+bk)^T / 32) (xWv^T+bv)
// B=4, S=2048, E=1024, fp32 in/out.  bf16 MFMA pipeline.
// R4 change: GEMM core switched 16x16x32 -> 32x32x16 MFMA (half the issue
// slots per FLOP; ubench ceiling 2495 vs 2075 TF). Per wave: 2x2 frags of
// 32x32, f32x16 acc. BK=64, 4 k-substeps of 16.
// LDS swizzle: row = 8 granules of 16B; physical slot = logical ^ (row&7);
// fragment logical granule for substep s = s*2 + (lane>>5); staging lane L
// stages chunk (L&7)^(L>>3) of row strip+(L>>3)  (all conflict-free).
// Fused epilogues: proj writes V transposed (vector stores); scores does
// exp + atomic rowsum; PV normalizes by 1/rowsum.
// ---------------------------------------------------------------------------

typedef __attribute__((ext_vector_type(8))) short bf16x8;
typedef __attribute__((ext_vector_type(16))) float f32x16;

__device__ __forceinline__ unsigned short f2bf(float f) {
  union { float f; uint32_t u; } x; x.f = f;
  uint32_t u = x.u;
  return (unsigned short)((u + 0x7fffu + ((u >> 16) & 1u)) >> 16);  // RNE
}

__device__ __forceinline__ void async_copy16(const void* g, void* l) {
  __builtin_amdgcn_global_load_lds(
      (const __attribute__((address_space(1))) void*)g,
      (__attribute__((address_space(3))) void*)l, 16, 0, 0);
}

// ---------------------------------------------------------------------------
// One merged fp32->bf16 convert for x, Wq, Wk, Wv
// ---------------------------------------------------------------------------
__global__ __launch_bounds__(256) void convert_all(
    const float* __restrict__ x, const float* __restrict__ Wq,
    const float* __restrict__ Wk, const float* __restrict__ Wv,
    unsigned short* __restrict__ xb, unsigned short* __restrict__ Wb) {
  const long X4 = (long)8192 * 1024 / 4;
  const long W4 = (long)1024 * 1024 / 4;
  long i = (long)blockIdx.x * 256 + threadIdx.x;
  const float* src; unsigned short* dst; long off;
  if (i < X4)             { src = x;  dst = xb;                    off = i; }
  else if (i < X4 + W4)   { src = Wq; dst = Wb;                    off = i - X4; }
  else if (i < X4 + 2*W4) { src = Wk; dst = Wb + (long)1024*1024;  off = i - X4 - W4; }
  else                    { src = Wv; dst = Wb + (long)2048*1024;  off = i - X4 - 2*W4; }
  const float4 v = ((const float4*)src)[off];
  ushort4 o;
  o.x = f2bf(v.x); o.y = f2bf(v.y); o.z = f2bf(v.z); o.w = f2bf(v.w);
  ((ushort4*)dst)[off] = o;
}

// ---------------------------------------------------------------------------
// C[M,N] = op( scale * (A[M,K] x B[N,K]^T) + bias )
// MODE 0 (PROJ):   bf16 out; z<2 -> normal rows; z==2 -> write V transposed
// MODE 1 (SCORES): bf16 out = exp(scale*acc); atomicAdd per-row sums
// MODE 2 (PV):     fp32 out = acc * (1/rowsum[row])
// 256 threads = 4 waves, 128x128 tile, BK=64, 32x32x16 bf16 MFMA.
// C/D layout (m74/m101): col = lane&31, row = (reg&3)+8*(reg>>2)+4*(lane>>5)
// A/B layout: X[m or n = lane&31][k = (lane>>5)*8 + j]
// ---------------------------------------------------------------------------
template <int MODE>
__global__ __launch_bounds__(256) void gemm_bt(
    const unsigned short* __restrict__ Ab, const unsigned short* __restrict__ Bb,
    unsigned short* __restrict__ Cb, float* __restrict__ Cf,
    unsigned short* __restrict__ VT,
    const float* __restrict__ bias0, const float* __restrict__ bias1,
    const float* __restrict__ bias2, float* __restrict__ rowsum,
    int K, int N, float scale, long sA, long sB, long sC) {
  __shared__ unsigned short As[128 * 64];
  __shared__ unsigned short Bs[128 * 64];

  const int z = blockIdx.z;
  const unsigned short* A  = Ab + (long)z * sA;
  const unsigned short* Bm = Bb + (long)z * sB;

  const int tid  = threadIdx.x;
  const int lane = tid & 63;
  const int wave = tid >> 6;
  const int l31  = lane & 31;
  const int khalf = lane >> 5;
  const int wm = (wave >> 1) * 64;
  const int wn = (wave & 1) * 64;

  const int tile_m = blockIdx.x * 128;
  const int tile_n = blockIdx.y * 128;

  // --- staging map: wave w covers rows [w*32, w*32+32), 4 instrs x 8 rows.
  // Lane L -> LDS slot L&7 of row strip+(L>>3); content = chunk (L&7)^(L>>3).
  const int rs8 = lane >> 3;
  const int kc  = (lane & 7) ^ rs8;
  const long lK = (long)K;
  const unsigned short* gA0 = A  + (long)(tile_m + wave * 32 + rs8) * lK + kc * 8;
  const unsigned short* gB0 = Bm + (long)(tile_n + wave * 32 + rs8) * lK + kc * 8;
  unsigned short* lA = &As[(wave * 32) * 64];
  unsigned short* lB = &Bs[(wave * 32) * 64];

  // --- fragment read bases; swizzle term row&7 == l31&7 (wm,wn mult of 64)
  const int sw = l31 & 7;
  const unsigned short* pA0 = &As[(wm + l31) * 64];
  const unsigned short* pA1 = pA0 + 32 * 64;
  const unsigned short* pB0 = &Bs[(wn + l31) * 64];
  const unsigned short* pB1 = pB0 + 32 * 64;

  f32x16 acc[2][2] = {};

  for (int k0 = 0; k0 < K; k0 += 64) {
    __syncthreads();  // previous-iter LDS readers done
#pragma unroll
    for (int t = 0; t < 4; ++t) {
      async_copy16(gA0 + (long)t * 8 * lK + k0, lA + t * 8 * 64);
      async_copy16(gB0 + (long)t * 8 * lK + k0, lB + t * 8 * 64);
    }
    __syncthreads();  // drain: LDS tile ready

#pragma unroll
    for (int s = 0; s < 4; ++s) {
      const int g = (((s * 2 + khalf) ^ sw) * 8);
      const bf16x8 a0 = *(const bf16x8*)(pA0 + g);
      const bf16x8 a1 = *(const bf16x8*)(pA1 + g);
      const bf16x8 b0 = *(const bf16x8*)(pB0 + g);
      const bf16x8 b1 = *(const bf16x8*)(pB1 + g);
      acc[0][0] = __builtin_amdgcn_mfma_f32_32x32x16_bf16(a0, b0, acc[0][0], 0, 0, 0);
      acc[0][1] = __builtin_amdgcn_mfma_f32_32x32x16_bf16(a0, b1, acc[0][1], 0, 0, 0);
      acc[1][0] = __builtin_amdgcn_mfma_f32_32x32x16_bf16(a1, b0, acc[1][0], 0, 0, 0);
      acc[1][1] = __builtin_amdgcn_mfma_f32_32x32x16_bf16(a1, b1, acc[1][1], 0, 0, 0);
    }
  }

  // ------------------------- epilogue -------------------------
  if (MODE == 0) {
    const float* bias = (z == 0) ? bias0 : (z == 1) ? bias1 : bias2;
    if (z == 2) {
      // write V transposed: VT[b][f][s]; tokens consecutive per reg-quad
#pragma unroll
      for (int jj = 0; jj < 2; ++jj) {
        const int col = tile_n + wn + jj * 32 + l31;  // feature f
        const float bv = bias[col];
#pragma unroll
        for (int ii = 0; ii < 2; ++ii) {
          const int rbase = tile_m + wm + ii * 32 + 4 * khalf;
#pragma unroll
          for (int g4 = 0; g4 < 4; ++g4) {
            const int row0 = rbase + 8 * g4;  // token; 4 consecutive
            const int b = row0 >> 11;
            const int sx = row0 & 2047;
            ushort4 o;
            o.x = f2bf(acc[ii][jj][4 * g4 + 0] + bv);
            o.y = f2bf(acc[ii][jj][4 * g4 + 1] + bv);
            o.z = f2bf(acc[ii][jj][4 * g4 + 2] + bv);
            o.w = f2bf(acc[ii][jj][4 * g4 + 3] + bv);
            *(ushort4*)&VT[(long)b * 1024 * 2048 + (long)col * 2048 + sx] = o;
          }
        }
      }
    } else {
      unsigned short* Cbz = Cb + (long)z * sC;
#pragma unroll
      for (int jj = 0; jj < 2; ++jj) {
        const int col = tile_n + wn + jj * 32 + l31;
        const float bv = bias[col];
#pragma unroll
        for (int ii = 0; ii < 2; ++ii) {
          const int rbase = tile_m + wm + ii * 32 + 4 * khalf;
#pragma unroll
          for (int reg = 0; reg < 16; ++reg) {
            const int row = rbase + (reg & 3) + 8 * (reg >> 2);
            Cbz[(long)row * N + col] = f2bf(acc[ii][jj][reg] + bv);
          }
        }
      }
    }
  } else if (MODE == 1) {
    // exp epilogue + row-sum atomics
    unsigned short* Cbz = Cb + (long)z * sC;
    float part[2][16];
#pragma unroll
    for (int ii = 0; ii < 2; ++ii)
#pragma unroll
      for (int reg = 0; reg < 16; ++reg) part[ii][reg] = 0.0f;
#pragma unroll
    for (int jj = 0; jj < 2; ++jj) {
      const int col = tile_n + wn + jj * 32 + l31;
#pragma unroll
      for (int ii = 0; ii < 2; ++ii) {
        const int rbase = tile_m + wm + ii * 32 + 4 * khalf;
#pragma unroll
        for (int reg = 0; reg < 16; ++reg) {
          const float e = __expf(acc[ii][jj][reg] * scale);
          part[ii][reg] += e;
          const int row = rbase + (reg & 3) + 8 * (reg >> 2);
          Cbz[(long)row * N + col] = f2bf(e);
        }
      }
    }
    // reduce across the 32 lanes (l31) sharing each row
#pragma unroll
    for (int ii = 0; ii < 2; ++ii)
#pragma unroll
      for (int reg = 0; reg < 16; ++reg)
#pragma unroll
        for (int o = 1; o < 32; o <<= 1)
          part[ii][reg] += __shfl_xor(part[ii][reg], o);
    if (l31 == 0) {  // lanes 0 and 32 (khalf 0/1) cover disjoint row sets
#pragma unroll
      for (int ii = 0; ii < 2; ++ii) {
        const int rbase = tile_m + wm + ii * 32 + 4 * khalf;
#pragma unroll
        for (int reg = 0; reg < 16; ++reg) {
          const int row = rbase + (reg & 3) + 8 * (reg >> 2);
          atomicAdd(&rowsum[z * 2048 + row], part[ii][reg]);
        }
      }
    }
  } else {
    // PV: normalize by rowsum
    float* Cfz = Cf + (long)z * sC;
    float inv[2][16];
#pragma unroll
    for (int ii = 0; ii < 2; ++ii) {
      const int rbase = tile_m + wm + ii * 32 + 4 * khalf;
#pragma unroll
      for (int reg = 0; reg < 16; ++reg) {
        const int row = rbase + (reg & 3) + 8 * (reg >> 2);
        inv[ii][reg] = 1.0f / rowsum[z * 2048 + row];
      }
    }
#pragma unroll
    for (int jj = 0; jj < 2; ++jj) {
      const int col = tile_n + wn + jj * 32 + l31;
#pragma unroll
      for (int ii = 0; ii < 2; ++ii) {
        const int rbase = tile_m + wm + ii * 32 + 4 * khalf;
#pragma unroll
        for (int reg = 0; reg < 16; ++reg) {
          const int row = rbase + (reg & 3) + 8 * (reg >> 2);
          Cfz[(long)row * N + col] = acc[ii][jj][reg] * inv[ii][reg];
        }
      }
    }
  }
}

// ---------------------------------------------------------------------------
extern "C" void kernel_launch(void* const* d_in, const int* in_sizes, int n_in,
                              void* d_out, int out_size, void* d_ws, size_t ws_size,
                              hipStream_t stream) {
  const float* x  = (const float*)d_in[0];
  const float* Wq = (const float*)d_in[1];
  const float* bq = (const float*)d_in[2];
  const float* Wk = (const float*)d_in[3];
  const float* bk = (const float*)d_in[4];
  const float* Wv = (const float*)d_in[5];
  const float* bv = (const float*)d_in[6];
  float* out = (float*)d_out;

  constexpr int Bt = 4, S = 2048, E = 1024;
  constexpr int M = Bt * S;  // 8192

  // ws layout (bf16): x_bf | W_bf(3) | Q | K | VT | P(exp scores) | rowsum(f32)
  unsigned short* xb = (unsigned short*)d_ws;
  unsigned short* Wb = xb + (size_t)M * E;
  unsigned short* Q  = Wb + (size_t)3 * E * E;
  unsigned short* Kb = Q + (size_t)M * E;
  unsigned short* VT = Kb + (size_t)M * E;
  unsigned short* P  = VT + (size_t)M * E;
  float* rowsum = (float*)(P + (size_t)Bt * S * S);

  // 0) zero the row-sum accumulators (ws is poisoned 0xAA each launch)
  hipMemsetAsync(rowsum, 0, (size_t)M * sizeof(float), stream);

  // 1) converts
  const int conv_blocks = (M * E / 4 + 3 * (E * E / 4)) / 256;
  convert_all<<<dim3(conv_blocks), dim3(256), 0, stream>>>(x, Wq, Wk, Wv, xb, Wb);

  // 2) projections: z in {Q,K,V}; y = x W^T + b; V written transposed
  gemm_bt<0><<<dim3(M / 128, E / 128, 3), dim3(256), 0, stream>>>(
      xb, Wb, Q, nullptr, VT, bq, bk, bv, nullptr, E, E, 1.0f,
      0L, (long)E * E, (long)M * E);

  // 3) P = exp(Q K^T / 32) (unnormalized) + row sums
  gemm_bt<1><<<dim3(S / 128, S / 128, Bt), dim3(256), 0, stream>>>(
      Q, Kb, P, nullptr, nullptr, nullptr, nullptr, nullptr, rowsum,
      E, S, 1.0f / 32.0f, (long)S * E, (long)S * E, (long)S * S);

  // 4) out = (P V) / rowsum   (fp32 out)
  gemm_bt<2><<<dim3(S / 128, E / 128, Bt), dim3(256), 0, stream>>>(
      P, VT, nullptr, out, nullptr, nullptr, nullptr, nullptr, rowsum,
      S, E, 1.0f, (long)S * S, (long)E * S, (long)S * E);
}

// Round 5
// 261.221 us; speedup vs baseline: 1.0550x; 1.0550x over previous
//
#include <hip/hip_runtime.h>
#include <hip/hip_bf16.h>
#include <cstdint>

// ---------------------------------------------------------------------------
// AttentionModel: out = softmax((xWq^T+bq)(xWk^T+bk)^T / 32) (xWv^T+bv)
// B=4, S=2048, E=1024, fp32 in/out.  bf16 MFMA pipeline.
// R5: revert to the R3 GEMM core (16x16x32 MFMA, BK=64, XOR granule swizzle
// — the proven 0-conflict layout; R4's 32x32x16 pattern re-introduced 4-way
// LDS conflicts and regressed). rowsum zeroing folded into convert_all
// (drops the hipMemsetAsync dispatch).
// LDS swizzle (BK=64): row = 8 granules of 16B, physical slot = kc ^ (row&7);
// fragment granule for substep s = (s*4+quad) ^ (row&7); staging lane L
// stages chunk (L&7)^(L>>3) of row strip+(L>>3). All conflict-free (R3-
// verified: SQ_LDS_BANK_CONFLICT == 0).
// Fused epilogues: proj writes V transposed; scores does exp + atomic
// rowsum; PV normalizes by 1/rowsum.
// ---------------------------------------------------------------------------

typedef __attribute__((ext_vector_type(8))) short bf16x8;
typedef __attribute__((ext_vector_type(4))) float f32x4;

__device__ __forceinline__ unsigned short f2bf(float f) {
  union { float f; uint32_t u; } x; x.f = f;
  uint32_t u = x.u;
  return (unsigned short)((u + 0x7fffu + ((u >> 16) & 1u)) >> 16);  // RNE
}

__device__ __forceinline__ void async_copy16(const void* g, void* l) {
  __builtin_amdgcn_global_load_lds(
      (const __attribute__((address_space(1))) void*)g,
      (__attribute__((address_space(3))) void*)l, 16, 0, 0);
}

// ---------------------------------------------------------------------------
// Merged fp32->bf16 convert for x, Wq, Wk, Wv; last block zeroes rowsum.
// ---------------------------------------------------------------------------
__global__ __launch_bounds__(256) void convert_all(
    const float* __restrict__ x, const float* __restrict__ Wq,
    const float* __restrict__ Wk, const float* __restrict__ Wv,
    unsigned short* __restrict__ xb, unsigned short* __restrict__ Wb,
    float* __restrict__ rowsum) {
  const long X4 = (long)8192 * 1024 / 4;
  const long W4 = (long)1024 * 1024 / 4;
  if (blockIdx.x == gridDim.x - 1) {
    // zero 8192 fp32 rowsums (ws is poisoned 0xAA before every launch)
    float4* r = (float4*)rowsum;
#pragma unroll
    for (int t = 0; t < 8; ++t)
      r[threadIdx.x + t * 256] = float4{0.f, 0.f, 0.f, 0.f};
    return;
  }
  long i = (long)blockIdx.x * 256 + threadIdx.x;
  const float* src; unsigned short* dst; long off;
  if (i < X4)             { src = x;  dst = xb;                    off = i; }
  else if (i < X4 + W4)   { src = Wq; dst = Wb;                    off = i - X4; }
  else if (i < X4 + 2*W4) { src = Wk; dst = Wb + (long)1024*1024;  off = i - X4 - W4; }
  else                    { src = Wv; dst = Wb + (long)2048*1024;  off = i - X4 - 2*W4; }
  const float4 v = ((const float4*)src)[off];
  ushort4 o;
  o.x = f2bf(v.x); o.y = f2bf(v.y); o.z = f2bf(v.z); o.w = f2bf(v.w);
  ((ushort4*)dst)[off] = o;
}

// ---------------------------------------------------------------------------
// C[M,N] = op( scale * (A[M,K] x B[N,K]^T) + bias )
// MODE 0 (PROJ):   bf16 out; z<2 -> normal rows; z==2 -> write V transposed
// MODE 1 (SCORES): bf16 out = exp(scale*acc); atomicAdd per-row sums
// MODE 2 (PV):     fp32 out = acc * (1/rowsum[row])
// 256 threads = 4 waves, 128x128 tile, BK=64, 16x16x32 bf16 MFMA.
// ---------------------------------------------------------------------------
template <int MODE>
__global__ __launch_bounds__(256) void gemm_bt(
    const unsigned short* __restrict__ Ab, const unsigned short* __restrict__ Bb,
    unsigned short* __restrict__ Cb, float* __restrict__ Cf,
    unsigned short* __restrict__ VT,
    const float* __restrict__ bias0, const float* __restrict__ bias1,
    const float* __restrict__ bias2, float* __restrict__ rowsum,
    int K, int N, float scale, long sA, long sB, long sC) {
  __shared__ unsigned short As[128 * 64];
  __shared__ unsigned short Bs[128 * 64];

  const int z = blockIdx.z;
  const unsigned short* A  = Ab + (long)z * sA;
  const unsigned short* Bm = Bb + (long)z * sB;

  const int tid  = threadIdx.x;
  const int lane = tid & 63;
  const int wave = tid >> 6;
  const int l15  = lane & 15;
  const int quad = lane >> 4;
  const int wm = (wave >> 1) * 64;
  const int wn = (wave & 1) * 64;

  const int tile_m = blockIdx.x * 128;
  const int tile_n = blockIdx.y * 128;

  // --- staging map: wave w covers rows [w*32, w*32+32), 4 instrs x 8 rows.
  // Lane L -> LDS slot L&7 of row strip+(L>>3); content = chunk (L&7)^(L>>3).
  const int rs8 = lane >> 3;
  const int kc  = (lane & 7) ^ rs8;
  const long lK = (long)K;
  const unsigned short* gA0 = A  + (long)(tile_m + wave * 32 + rs8) * lK + kc * 8;
  const unsigned short* gB0 = Bm + (long)(tile_n + wave * 32 + rs8) * lK + kc * 8;
  unsigned short* lA = &As[(wave * 32) * 64];
  unsigned short* lB = &Bs[(wave * 32) * 64];

  // --- fragment granule select: physical = (s*4+quad) ^ (row&7), row&7=l15&7
  const int g0 = (0 * 4 + quad) ^ (l15 & 7);
  const int g1 = (1 * 4 + quad) ^ (l15 & 7);

  f32x4 acc[4][4] = {};

  for (int k0 = 0; k0 < K; k0 += 64) {
    __syncthreads();  // previous-iter LDS readers done
#pragma unroll
    for (int t = 0; t < 4; ++t) {
      async_copy16(gA0 + (long)t * 8 * lK + k0, lA + t * 8 * 64);
      async_copy16(gB0 + (long)t * 8 * lK + k0, lB + t * 8 * 64);
    }
    __syncthreads();  // drain: LDS tile ready

#pragma unroll
    for (int s = 0; s < 2; ++s) {
      const int gs = s ? g1 : g0;
      bf16x8 af[4], bfr[4];
#pragma unroll
      for (int i = 0; i < 4; ++i)
        af[i] = *(const bf16x8*)&As[(wm + i * 16 + l15) * 64 + gs * 8];
#pragma unroll
      for (int j = 0; j < 4; ++j)
        bfr[j] = *(const bf16x8*)&Bs[(wn + j * 16 + l15) * 64 + gs * 8];
#pragma unroll
      for (int i = 0; i < 4; ++i)
#pragma unroll
        for (int j = 0; j < 4; ++j)
          acc[i][j] = __builtin_amdgcn_mfma_f32_16x16x32_bf16(af[i], bfr[j], acc[i][j], 0, 0, 0);
    }
  }

  // ------------------------- epilogue -------------------------
  // C/D layout: col = lane&15, row = quad*4 + reg (m89-verified)
  if (MODE == 0) {
    const float* bias = (z == 0) ? bias0 : (z == 1) ? bias1 : bias2;
    if (z == 2) {
      // write V transposed: VT[b][f][s], b = row>>11, s = row&2047
#pragma unroll
      for (int j = 0; j < 4; ++j) {
        const int col = tile_n + wn + j * 16 + l15;  // feature f
        const float bv = bias[col];
#pragma unroll
        for (int i = 0; i < 4; ++i) {
          const int row0 = tile_m + wm + i * 16 + quad * 4;  // token
          const int b = row0 >> 11;
          const int sx = row0 & 2047;
          ushort4 o;
          o.x = f2bf(acc[i][j][0] + bv);
          o.y = f2bf(acc[i][j][1] + bv);
          o.z = f2bf(acc[i][j][2] + bv);
          o.w = f2bf(acc[i][j][3] + bv);
          *(ushort4*)&VT[(long)b * 1024 * 2048 + (long)col * 2048 + sx] = o;
        }
      }
    } else {
      unsigned short* Cbz = Cb + (long)z * sC;
#pragma unroll
      for (int j = 0; j < 4; ++j) {
        const int col = tile_n + wn + j * 16 + l15;
        const float bv = bias[col];
#pragma unroll
        for (int i = 0; i < 4; ++i) {
          const int row0 = tile_m + wm + i * 16 + quad * 4;
#pragma unroll
          for (int r = 0; r < 4; ++r)
            Cbz[(long)(row0 + r) * N + col] = f2bf(acc[i][j][r] + bv);
        }
      }
    }
  } else if (MODE == 1) {
    // exp epilogue + row-sum atomics
    unsigned short* Cbz = Cb + (long)z * sC;
    float part[16];
#pragma unroll
    for (int t = 0; t < 16; ++t) part[t] = 0.0f;
#pragma unroll
    for (int j = 0; j < 4; ++j) {
      const int col = tile_n + wn + j * 16 + l15;
#pragma unroll
      for (int i = 0; i < 4; ++i) {
        const int row0 = tile_m + wm + i * 16 + quad * 4;
#pragma unroll
        for (int r = 0; r < 4; ++r) {
          const float e = __expf(acc[i][j][r] * scale);
          part[i * 4 + r] += e;
          Cbz[(long)(row0 + r) * N + col] = f2bf(e);
        }
      }
    }
    // reduce across the 16 lanes (l15) sharing each row
#pragma unroll
    for (int t = 0; t < 16; ++t)
#pragma unroll
      for (int o = 1; o < 16; o <<= 1)
        part[t] += __shfl_xor(part[t], o);
    if (l15 == 0) {
#pragma unroll
      for (int i = 0; i < 4; ++i) {
        const int row0 = tile_m + wm + i * 16 + quad * 4;
#pragma unroll
        for (int r = 0; r < 4; ++r)
          atomicAdd(&rowsum[z * 2048 + row0 + r], part[i * 4 + r]);
      }
    }
  } else {
    // PV: normalize by rowsum
    float* Cfz = Cf + (long)z * sC;
    float inv[16];
#pragma unroll
    for (int i = 0; i < 4; ++i) {
      const int row0 = tile_m + wm + i * 16 + quad * 4;
#pragma unroll
      for (int r = 0; r < 4; ++r)
        inv[i * 4 + r] = 1.0f / rowsum[z * 2048 + row0 + r];
    }
#pragma unroll
    for (int j = 0; j < 4; ++j) {
      const int col = tile_n + wn + j * 16 + l15;
#pragma unroll
      for (int i = 0; i < 4; ++i) {
        const int row0 = tile_m + wm + i * 16 + quad * 4;
#pragma unroll
        for (int r = 0; r < 4; ++r)
          Cfz[(long)(row0 + r) * N + col] = acc[i][j][r] * inv[i * 4 + r];
      }
    }
  }
}

// ---------------------------------------------------------------------------
extern "C" void kernel_launch(void* const* d_in, const int* in_sizes, int n_in,
                              void* d_out, int out_size, void* d_ws, size_t ws_size,
                              hipStream_t stream) {
  const float* x  = (const float*)d_in[0];
  const float* Wq = (const float*)d_in[1];
  const float* bq = (const float*)d_in[2];
  const float* Wk = (const float*)d_in[3];
  const float* bk = (const float*)d_in[4];
  const float* Wv = (const float*)d_in[5];
  const float* bv = (const float*)d_in[6];
  float* out = (float*)d_out;

  constexpr int Bt = 4, S = 2048, E = 1024;
  constexpr int M = Bt * S;  // 8192

  // ws layout (bf16): x_bf | W_bf(3) | Q | K | VT | P(exp scores) | rowsum(f32)
  unsigned short* xb = (unsigned short*)d_ws;
  unsigned short* Wb = xb + (size_t)M * E;
  unsigned short* Q  = Wb + (size_t)3 * E * E;
  unsigned short* Kb = Q + (size_t)M * E;
  unsigned short* VT = Kb + (size_t)M * E;
  unsigned short* P  = VT + (size_t)M * E;
  float* rowsum = (float*)(P + (size_t)Bt * S * S);

  // 1) converts + rowsum zeroing (one launch; ordering before scores is
  //    guaranteed by the intervening proj dispatch)
  const int conv_blocks = (M * E / 4 + 3 * (E * E / 4)) / 256 + 1;
  convert_all<<<dim3(conv_blocks), dim3(256), 0, stream>>>(x, Wq, Wk, Wv, xb, Wb, rowsum);

  // 2) projections: z in {Q,K,V}; y = x W^T + b; V written transposed
  gemm_bt<0><<<dim3(M / 128, E / 128, 3), dim3(256), 0, stream>>>(
      xb, Wb, Q, nullptr, VT, bq, bk, bv, nullptr, E, E, 1.0f,
      0L, (long)E * E, (long)M * E);

  // 3) P = exp(Q K^T / 32) (unnormalized) + row sums
  gemm_bt<1><<<dim3(S / 128, S / 128, Bt), dim3(256), 0, stream>>>(
      Q, Kb, P, nullptr, nullptr, nullptr, nullptr, nullptr, rowsum,
      E, S, 1.0f / 32.0f, (long)S * E, (long)S * E, (long)S * S);

  // 4) out = (P V) / rowsum   (fp32 out)
  gemm_bt<2><<<dim3(S / 128, E / 128, Bt), dim3(256), 0, stream>>>(
      P, VT, nullptr, out, nullptr, nullptr, nullptr, nullptr, rowsum,
      S, E, 1.0f, (long)S * S, (long)E * S, (long)S * E);
}

// Round 6
// 233.260 us; speedup vs baseline: 1.1815x; 1.1199x over previous
//
#include <hip/hip_runtime.h>
#include <hip/hip_bf16.h>
#include <cstdint>

// ---------------------------------------------------------------------------
// AttentionModel: out = softmax((xWq^T+bq)(xWk^T+bk)^T / 32) (xWv^T+bv)
// B=4, S=2048, E=1024, fp32 in/out.  bf16 MFMA pipeline.
// R6: __launch_bounds__(256, 4) on the GEMM — cap unified VGPR+AGPR at 128
// so 4 blocks/CU are co-resident (was 3 at 156 regs). We are latency-bound:
// per-block-iter wall ~1884 cyc vs ~465 cyc compute content; one more
// resident block per CU shrinks the exposed drain-convoy.
// Core (R3/R5-proven): 16x16x32 MFMA, BK=64, XOR granule swizzle, 0 LDS
// conflicts. Fused epilogues: proj writes V transposed; scores does exp +
// atomic rowsum; PV normalizes by 1/rowsum.
// ---------------------------------------------------------------------------

typedef __attribute__((ext_vector_type(8))) short bf16x8;
typedef __attribute__((ext_vector_type(4))) float f32x4;

__device__ __forceinline__ unsigned short f2bf(float f) {
  union { float f; uint32_t u; } x; x.f = f;
  uint32_t u = x.u;
  return (unsigned short)((u + 0x7fffu + ((u >> 16) & 1u)) >> 16);  // RNE
}

__device__ __forceinline__ void async_copy16(const void* g, void* l) {
  __builtin_amdgcn_global_load_lds(
      (const __attribute__((address_space(1))) void*)g,
      (__attribute__((address_space(3))) void*)l, 16, 0, 0);
}

// ---------------------------------------------------------------------------
// Merged fp32->bf16 convert for x, Wq, Wk, Wv; last block zeroes rowsum.
// ---------------------------------------------------------------------------
__global__ __launch_bounds__(256) void convert_all(
    const float* __restrict__ x, const float* __restrict__ Wq,
    const float* __restrict__ Wk, const float* __restrict__ Wv,
    unsigned short* __restrict__ xb, unsigned short* __restrict__ Wb,
    float* __restrict__ rowsum) {
  const long X4 = (long)8192 * 1024 / 4;
  const long W4 = (long)1024 * 1024 / 4;
  if (blockIdx.x == gridDim.x - 1) {
    float4* r = (float4*)rowsum;
#pragma unroll
    for (int t = 0; t < 8; ++t)
      r[threadIdx.x + t * 256] = float4{0.f, 0.f, 0.f, 0.f};
    return;
  }
  long i = (long)blockIdx.x * 256 + threadIdx.x;
  const float* src; unsigned short* dst; long off;
  if (i < X4)             { src = x;  dst = xb;                    off = i; }
  else if (i < X4 + W4)   { src = Wq; dst = Wb;                    off = i - X4; }
  else if (i < X4 + 2*W4) { src = Wk; dst = Wb + (long)1024*1024;  off = i - X4 - W4; }
  else                    { src = Wv; dst = Wb + (long)2048*1024;  off = i - X4 - 2*W4; }
  const float4 v = ((const float4*)src)[off];
  ushort4 o;
  o.x = f2bf(v.x); o.y = f2bf(v.y); o.z = f2bf(v.z); o.w = f2bf(v.w);
  ((ushort4*)dst)[off] = o;
}

// ---------------------------------------------------------------------------
// C[M,N] = op( scale * (A[M,K] x B[N,K]^T) + bias )
// MODE 0 (PROJ):   bf16 out; z<2 -> normal rows; z==2 -> write V transposed
// MODE 1 (SCORES): bf16 out = exp(scale*acc); atomicAdd per-row sums
// MODE 2 (PV):     fp32 out = acc * (1/rowsum[row])
// 256 threads = 4 waves, 128x128 tile, BK=64, 16x16x32 bf16 MFMA.
// __launch_bounds__(256,4): 4 waves/EU -> <=128 unified regs -> 4 blocks/CU.
// ---------------------------------------------------------------------------
template <int MODE>
__global__ __launch_bounds__(256, 4) void gemm_bt(
    const unsigned short* __restrict__ Ab, const unsigned short* __restrict__ Bb,
    unsigned short* __restrict__ Cb, float* __restrict__ Cf,
    unsigned short* __restrict__ VT,
    const float* __restrict__ bias0, const float* __restrict__ bias1,
    const float* __restrict__ bias2, float* __restrict__ rowsum,
    int K, int N, float scale, long sA, long sB, long sC) {
  __shared__ unsigned short As[128 * 64];
  __shared__ unsigned short Bs[128 * 64];

  const int z = blockIdx.z;
  const unsigned short* A  = Ab + (long)z * sA;
  const unsigned short* Bm = Bb + (long)z * sB;

  const int tid  = threadIdx.x;
  const int lane = tid & 63;
  const int wave = tid >> 6;
  const int l15  = lane & 15;
  const int quad = lane >> 4;
  const int wm = (wave >> 1) * 64;
  const int wn = (wave & 1) * 64;

  const int tile_m = blockIdx.x * 128;
  const int tile_n = blockIdx.y * 128;

  // --- staging map: wave w covers rows [w*32, w*32+32), 4 instrs x 8 rows.
  // Lane L -> LDS slot L&7 of row strip+(L>>3); content = chunk (L&7)^(L>>3).
  const int rs8 = lane >> 3;
  const int kc  = (lane & 7) ^ rs8;
  const long lK = (long)K;
  const unsigned short* gA0 = A  + (long)(tile_m + wave * 32 + rs8) * lK + kc * 8;
  const unsigned short* gB0 = Bm + (long)(tile_n + wave * 32 + rs8) * lK + kc * 8;
  unsigned short* lA = &As[(wave * 32) * 64];
  unsigned short* lB = &Bs[(wave * 32) * 64];

  // --- fragment granule select: physical = (s*4+quad) ^ (row&7), row&7=l15&7
  const int g0 = (0 * 4 + quad) ^ (l15 & 7);
  const int g1 = (1 * 4 + quad) ^ (l15 & 7);

  f32x4 acc[4][4] = {};

  for (int k0 = 0; k0 < K; k0 += 64) {
    __syncthreads();  // previous-iter LDS readers done
#pragma unroll
    for (int t = 0; t < 4; ++t) {
      async_copy16(gA0 + (long)t * 8 * lK + k0, lA + t * 8 * 64);
      async_copy16(gB0 + (long)t * 8 * lK + k0, lB + t * 8 * 64);
    }
    __syncthreads();  // drain: LDS tile ready

#pragma unroll
    for (int s = 0; s < 2; ++s) {
      const int gs = s ? g1 : g0;
      bf16x8 af[4], bfr[4];
#pragma unroll
      for (int i = 0; i < 4; ++i)
        af[i] = *(const bf16x8*)&As[(wm + i * 16 + l15) * 64 + gs * 8];
#pragma unroll
      for (int j = 0; j < 4; ++j)
        bfr[j] = *(const bf16x8*)&Bs[(wn + j * 16 + l15) * 64 + gs * 8];
#pragma unroll
      for (int i = 0; i < 4; ++i)
#pragma unroll
        for (int j = 0; j < 4; ++j)
          acc[i][j] = __builtin_amdgcn_mfma_f32_16x16x32_bf16(af[i], bfr[j], acc[i][j], 0, 0, 0);
    }
  }

  // ------------------------- epilogue -------------------------
  // C/D layout: col = lane&15, row = quad*4 + reg (m89-verified)
  if (MODE == 0) {
    const float* bias = (z == 0) ? bias0 : (z == 1) ? bias1 : bias2;
    if (z == 2) {
      // write V transposed: VT[b][f][s], b = row>>11, s = row&2047
#pragma unroll
      for (int j = 0; j < 4; ++j) {
        const int col = tile_n + wn + j * 16 + l15;  // feature f
        const float bv = bias[col];
#pragma unroll
        for (int i = 0; i < 4; ++i) {
          const int row0 = tile_m + wm + i * 16 + quad * 4;  // token
          const int b = row0 >> 11;
          const int sx = row0 & 2047;
          ushort4 o;
          o.x = f2bf(acc[i][j][0] + bv);
          o.y = f2bf(acc[i][j][1] + bv);
          o.z = f2bf(acc[i][j][2] + bv);
          o.w = f2bf(acc[i][j][3] + bv);
          *(ushort4*)&VT[(long)b * 1024 * 2048 + (long)col * 2048 + sx] = o;
        }
      }
    } else {
      unsigned short* Cbz = Cb + (long)z * sC;
#pragma unroll
      for (int j = 0; j < 4; ++j) {
        const int col = tile_n + wn + j * 16 + l15;
        const float bv = bias[col];
#pragma unroll
        for (int i = 0; i < 4; ++i) {
          const int row0 = tile_m + wm + i * 16 + quad * 4;
#pragma unroll
          for (int r = 0; r < 4; ++r)
            Cbz[(long)(row0 + r) * N + col] = f2bf(acc[i][j][r] + bv);
        }
      }
    }
  } else if (MODE == 1) {
    // exp epilogue + row-sum atomics
    unsigned short* Cbz = Cb + (long)z * sC;
    float part[16];
#pragma unroll
    for (int t = 0; t < 16; ++t) part[t] = 0.0f;
#pragma unroll
    for (int j = 0; j < 4; ++j) {
      const int col = tile_n + wn + j * 16 + l15;
#pragma unroll
      for (int i = 0; i < 4; ++i) {
        const int row0 = tile_m + wm + i * 16 + quad * 4;
#pragma unroll
        for (int r = 0; r < 4; ++r) {
          const float e = __expf(acc[i][j][r] * scale);
          part[i * 4 + r] += e;
          Cbz[(long)(row0 + r) * N + col] = f2bf(e);
        }
      }
    }
    // reduce across the 16 lanes (l15) sharing each row
#pragma unroll
    for (int t = 0; t < 16; ++t)
#pragma unroll
      for (int o = 1; o < 16; o <<= 1)
        part[t] += __shfl_xor(part[t], o);
    if (l15 == 0) {
#pragma unroll
      for (int i = 0; i < 4; ++i) {
        const int row0 = tile_m + wm + i * 16 + quad * 4;
#pragma unroll
        for (int r = 0; r < 4; ++r)
          atomicAdd(&rowsum[z * 2048 + row0 + r], part[i * 4 + r]);
      }
    }
  } else {
    // PV: normalize by rowsum
    float* Cfz = Cf + (long)z * sC;
    float inv[16];
#pragma unroll
    for (int i = 0; i < 4; ++i) {
      const int row0 = tile_m + wm + i * 16 + quad * 4;
#pragma unroll
      for (int r = 0; r < 4; ++r)
        inv[i * 4 + r] = 1.0f / rowsum[z * 2048 + row0 + r];
    }
#pragma unroll
    for (int j = 0; j < 4; ++j) {
      const int col = tile_n + wn + j * 16 + l15;
#pragma unroll
      for (int i = 0; i < 4; ++i) {
        const int row0 = tile_m + wm + i * 16 + quad * 4;
#pragma unroll
        for (int r = 0; r < 4; ++r)
          Cfz[(long)(row0 + r) * N + col] = acc[i][j][r] * inv[i * 4 + r];
      }
    }
  }
}

// ---------------------------------------------------------------------------
extern "C" void kernel_launch(void* const* d_in, const int* in_sizes, int n_in,
                              void* d_out, int out_size, void* d_ws, size_t ws_size,
                              hipStream_t stream) {
  const float* x  = (const float*)d_in[0];
  const float* Wq = (const float*)d_in[1];
  const float* bq = (const float*)d_in[2];
  const float* Wk = (const float*)d_in[3];
  const float* bk = (const float*)d_in[4];
  const float* Wv = (const float*)d_in[5];
  const float* bv = (const float*)d_in[6];
  float* out = (float*)d_out;

  constexpr int Bt = 4, S = 2048, E = 1024;
  constexpr int M = Bt * S;  // 8192

  // ws layout (bf16): x_bf | W_bf(3) | Q | K | VT | P(exp scores) | rowsum(f32)
  unsigned short* xb = (unsigned short*)d_ws;
  unsigned short* Wb = xb + (size_t)M * E;
  unsigned short* Q  = Wb + (size_t)3 * E * E;
  unsigned short* Kb = Q + (size_t)M * E;
  unsigned short* VT = Kb + (size_t)M * E;
  unsigned short* P  = VT + (size_t)M * E;
  float* rowsum = (float*)(P + (size_t)Bt * S * S);

  // 1) converts + rowsum zeroing (one launch)
  const int conv_blocks = (M * E / 4 + 3 * (E * E / 4)) / 256 + 1;
  convert_all<<<dim3(conv_blocks), dim3(256), 0, stream>>>(x, Wq, Wk, Wv, xb, Wb, rowsum);

  // 2) projections: z in {Q,K,V}; y = x W^T + b; V written transposed
  gemm_bt<0><<<dim3(M / 128, E / 128, 3), dim3(256), 0, stream>>>(
      xb, Wb, Q, nullptr, VT, bq, bk, bv, nullptr, E, E, 1.0f,
      0L, (long)E * E, (long)M * E);

  // 3) P = exp(Q K^T / 32) (unnormalized) + row sums
  gemm_bt<1><<<dim3(S / 128, S / 128, Bt), dim3(256), 0, stream>>>(
      Q, Kb, P, nullptr, nullptr, nullptr, nullptr, nullptr, rowsum,
      E, S, 1.0f / 32.0f, (long)S * E, (long)S * E, (long)S * S);

  // 4) out = (P V) / rowsum   (fp32 out)
  gemm_bt<2><<<dim3(S / 128, E / 128, Bt), dim3(256), 0, stream>>>(
      P, VT, nullptr, out, nullptr, nullptr, nullptr, nullptr, rowsum,
      S, E, 1.0f, (long)S * S, (long)E * S, (long)S * E);
}